// Round 8
// baseline (1465.668 us; speedup 1.0000x reference)
//
#include <hip/hip_runtime.h>
#include <hip/hip_bf16.h>

#define MM 8192
#define NN 11008
#define KK 4096
#define PKW 2048    // packed int32 words per output row (each word = ONE byte-pair value)

#define BM 256
#define BN 256
#define BKI 128                 // K per tile (i8)
#define NTI (KK / BKI)          // 32 K-tiles

typedef __attribute__((ext_vector_type(4)))  float f32x4;
typedef __attribute__((ext_vector_type(4)))  int   i32x4;
typedef __attribute__((ext_vector_type(16))) int   i32x16;
typedef __attribute__((ext_vector_type(8)))  short s16x8;
typedef __attribute__((ext_vector_type(4)))  short s16x4;

typedef __attribute__((address_space(3))) unsigned char        lds_u8;
typedef const __attribute__((address_space(1))) unsigned char  glb_u8;

static __device__ __forceinline__ unsigned short f2bf(float f) {
  union { float f; unsigned int u; } v; v.f = f;
  unsigned int u = v.u;
  u += 0x7fffu + ((u >> 16) & 1u);   // RNE
  return (unsigned short)(u >> 16);
}

#if __has_builtin(__builtin_amdgcn_mfma_i32_32x32x32_i8)
#define HAVE_I8_MFMA 1
#else
#define HAVE_I8_MFMA 0
#endif

#if HAVE_I8_MFMA
// ---------------- quantize x: per-row absmax -> i8, PRE-SWIZZLED ----------------
// Row layout: 256 groups of 16 B per row; within each 128-B K-block (8 groups),
// group g stored at g ^ (row&7). GEMM stages linearly, reads with same XOR.

__global__ __launch_bounds__(256) void int4lin_quant_x(
    const float* __restrict__ X, signed char* __restrict__ O, float* __restrict__ xs)
{
  const int row  = blockIdx.x;
  const int t    = threadIdx.x;
  const int lane = t & 63;
  const int wave = t >> 6;
  const float* xr = X + (size_t)row * KK;

  f32x4 v[4];
  float mx = 0.0f;
#pragma unroll
  for (int j = 0; j < 4; ++j) {
    v[j] = *(const f32x4*)(xr + t * 16 + j * 4);
#pragma unroll
    for (int e = 0; e < 4; ++e) mx = fmaxf(mx, fabsf(v[j][e]));
  }
#pragma unroll
  for (int off = 32; off; off >>= 1) mx = fmaxf(mx, __shfl_xor(mx, off));
  __shared__ float red[4];
  if (lane == 0) red[wave] = mx;
  __syncthreads();
  mx = fmaxf(fmaxf(red[0], red[1]), fmaxf(red[2], red[3]));
  mx = fmaxf(mx, 1e-30f);
  const float rs = 127.0f / mx;
  if (t == 0) xs[row] = mx / 127.0f;

  i32x4 o;
#pragma unroll
  for (int w = 0; w < 4; ++w) {
    int acc = 0;
#pragma unroll
    for (int e = 0; e < 4; ++e) {
      int q = __float2int_rn(v[w][e] * rs);
      q = max(-127, min(127, q));
      acc |= (q & 0xff) << (8 * e);
    }
    o[w] = acc;
  }
  signed char* dst = O + (size_t)row * KK + ((t >> 3) << 7) + (((t & 7) ^ (row & 7)) << 4);
  *(i32x4*)dst = o;
}

// ---------------- quantize w: nibbles -> i8 q in [-7,8], PRE-SWIZZLED ----------------

__global__ void int4lin_quant_w(const int* __restrict__ P, signed char* __restrict__ O) {
  const int ntot = NN * 256;       // 16-byte groups
  int i = blockIdx.x * blockDim.x + threadIdx.x;
  const int stride = gridDim.x * blockDim.x;
  for (; i < ntot; i += stride) {
    const int row = i >> 8;
    const int gr  = i & 255;
    const int* src = P + (size_t)row * PKW + gr * 8;   // 8 words -> 16 i8
    i32x4 va = *(const i32x4*)src;
    i32x4 vb = *(const i32x4*)(src + 4);
    i32x4 o;
#pragma unroll
    for (int h = 0; h < 2; ++h) {
      i32x4 w = h ? vb : va;
#pragma unroll
      for (int p = 0; p < 2; ++p) {
        const int b0 = w[2 * p], b1 = w[2 * p + 1];
        const int q0 = (b0 & 15) - 7, q1 = ((b0 >> 4) & 15) - 7;
        const int q2 = (b1 & 15) - 7, q3 = ((b1 >> 4) & 15) - 7;
        o[h * 2 + p] = (q0 & 0xff) | ((q1 & 0xff) << 8) | ((q2 & 0xff) << 16) | ((q3 & 0xff) << 24);
      }
    }
    signed char* dst = O + (size_t)row * KK + ((gr >> 3) << 7) + (((gr & 7) ^ (row & 7)) << 4);
    *(i32x4*)dst = o;
  }
}

// ---------------- 256x256x128 i8 GEMM, R6 ring skeleton ----------------
// Per tile per wave: 32x mfma_i32_32x32x32_i8 (mf 0..3, nf 0..1, ks 0..3).
// Frag read: 16 B at row*128 + ((ks*2+half)^ (r5&7))*16, half = lane>>5.
// Ring (8 gloads/tile): SP1: A(t+1) q1,q3 | post-S1: B(t+2) q0-3 + A(t+2) q0,q2.
// Boundary vmcnt(6): tile t+1's newest load has exactly 6 issued after it.
// S1 safety: pre-S1 reads cover all B rows + A rows of q0 (wm0 mf01) and q2
// (wm1 mf01); post-S1 stages touch only q0,q2,B of the live buffer.

__global__ __launch_bounds__(512, 2) void int4lin_gemm_i8(
    const signed char* __restrict__ Ai,   // M x K i8, pre-swizzled
    const signed char* __restrict__ Bi,   // N x K i8, pre-swizzled
    const float* __restrict__ xs,
    const float* __restrict__ scale,
    const float* __restrict__ bias,
    float* __restrict__ C)
{
  __shared__ signed char As[2][BM * BKI];   // 2 x 32 KiB
  __shared__ signed char Bs[2][BN * BKI];   // 2 x 32 KiB -> 128 KiB

  const int tid  = threadIdx.x;
  const int lane = tid & 63;
  const int wave = tid >> 6;
  const int wm = wave >> 2;          // 0..1
  const int wn = wave & 3;           // 0..3

  // T1: bijective XCD swizzle (1376 = 8*172)
  const int bid = blockIdx.x;
  const int swz = (bid & 7) * 172 + (bid >> 3);
  const int bm = swz / 43;
  const int bn = swz - bm * 43;
  const size_t m0 = (size_t)bm * BM;
  const size_t n0 = (size_t)bn * BN;

  const int r5   = lane & 31;        // frag row/col
  const int half = lane >> 5;        // k-half within instruction
  const int rx7  = r5 & 7;           // T2 read-swizzle key

  i32x16 acc[4][2] = {};             // [mf][nf]

  const int arow = wm * 128;         // + mf*32 + r5
  const int brow = wn * 64;          // + nf*32 + r5

#define LDFI(base, row, ks) \
  (*(const i32x4*)((const signed char*)(base) + (size_t)(row) * BKI + ((((ks) * 2 + half) ^ rx7) << 4)))

  const int srow   = tid >> 3;         // 0..63
  const int scolb  = (tid & 7) << 4;   // byte offset within 128-B row

  auto stage_a_q = [&](int buf, int kt, int q) {
    __builtin_amdgcn_global_load_lds(
        (glb_u8*)(Ai + (m0 + q * 64 + srow) * KK + kt + scolb),
        (lds_u8*)((char*)&As[buf][0] + q * 8192 + tid * 16), 16, 0, 0);
  };
  auto stage_b_q = [&](int buf, int kt, int q) {
    __builtin_amdgcn_global_load_lds(
        (glb_u8*)(Bi + (n0 + q * 64 + srow) * KK + kt + scolb),
        (lds_u8*)((char*)&Bs[buf][0] + q * 8192 + tid * 16), 16, 0, 0);
  };

  // -------- prologue: tile0 fully (8), tile1 partially (6); vmcnt(6) --------
#pragma unroll
  for (int q = 0; q < 4; ++q) stage_b_q(0, 0, q);
  stage_a_q(0, 0, 0); stage_a_q(0, 0, 2);
  stage_a_q(0, 0, 1); stage_a_q(0, 0, 3);
#pragma unroll
  for (int q = 0; q < 4; ++q) stage_b_q(1, BKI, q);
  stage_a_q(1, BKI, 0); stage_a_q(1, BKI, 2);
  asm volatile("s_waitcnt vmcnt(6)\n\ts_barrier" ::: "memory");

#pragma unroll 1
  for (int t = 0; t < NTI; ++t) {
    const int rbuf = t & 1;
    const signed char* Ab = &As[rbuf][0];
    const signed char* Bb = &Bs[rbuf][0];
    i32x4 a[4], b0[4], b1[4];

    // SP1: stage A(t+1) late quarters; read B + A mf0; MFMA mf0
    if (t + 1 < NTI) {
      stage_a_q(rbuf ^ 1, (t + 1) * BKI, 1);
      stage_a_q(rbuf ^ 1, (t + 1) * BKI, 3);
    }
#pragma unroll
    for (int ks = 0; ks < 4; ++ks) b0[ks] = LDFI(Bb, brow + r5, ks);
#pragma unroll
    for (int ks = 0; ks < 4; ++ks) b1[ks] = LDFI(Bb, brow + 32 + r5, ks);
#pragma unroll
    for (int ks = 0; ks < 4; ++ks) a[ks] = LDFI(Ab, arow + r5, ks);
    __builtin_amdgcn_s_setprio(1);
#pragma unroll
    for (int ks = 0; ks < 4; ++ks) {
      acc[0][0] = __builtin_amdgcn_mfma_i32_32x32x32_i8(a[ks], b0[ks], acc[0][0], 0, 0, 0);
      acc[0][1] = __builtin_amdgcn_mfma_i32_32x32x32_i8(a[ks], b1[ks], acc[0][1], 0, 0, 0);
    }
    __builtin_amdgcn_s_setprio(0);

    // SP2: read A mf1; MFMA mf1
#pragma unroll
    for (int ks = 0; ks < 4; ++ks) a[ks] = LDFI(Ab, arow + 32 + r5, ks);
    __builtin_amdgcn_s_setprio(1);
#pragma unroll
    for (int ks = 0; ks < 4; ++ks) {
      acc[1][0] = __builtin_amdgcn_mfma_i32_32x32x32_i8(a[ks], b0[ks], acc[1][0], 0, 0, 0);
      acc[1][1] = __builtin_amdgcn_mfma_i32_32x32x32_i8(a[ks], b1[ks], acc[1][1], 0, 0, 0);
    }
    __builtin_amdgcn_s_setprio(0);

    // S1: all waves' B reads + A q0/q2 reads complete
    asm volatile("s_barrier" ::: "memory");

    // post-S1: stage B(t+2) + A(t+2) early into live buffer
    if (t + 2 < NTI) {
#pragma unroll
      for (int q = 0; q < 4; ++q) stage_b_q(rbuf, (t + 2) * BKI, q);
      stage_a_q(rbuf, (t + 2) * BKI, 0);
      stage_a_q(rbuf, (t + 2) * BKI, 2);
    }

    // SP3: read A mf2; MFMA mf2
#pragma unroll
    for (int ks = 0; ks < 4; ++ks) a[ks] = LDFI(Ab, arow + 64 + r5, ks);
    __builtin_amdgcn_s_setprio(1);
#pragma unroll
    for (int ks = 0; ks < 4; ++ks) {
      acc[2][0] = __builtin_amdgcn_mfma_i32_32x32x32_i8(a[ks], b0[ks], acc[2][0], 0, 0, 0);
      acc[2][1] = __builtin_amdgcn_mfma_i32_32x32x32_i8(a[ks], b1[ks], acc[2][1], 0, 0, 0);
    }
    __builtin_amdgcn_s_setprio(0);

    // SP4: read A mf3; MFMA mf3
#pragma unroll
    for (int ks = 0; ks < 4; ++ks) a[ks] = LDFI(Ab, arow + 96 + r5, ks);
    __builtin_amdgcn_s_setprio(1);
#pragma unroll
    for (int ks = 0; ks < 4; ++ks) {
      acc[3][0] = __builtin_amdgcn_mfma_i32_32x32x32_i8(a[ks], b0[ks], acc[3][0], 0, 0, 0);
      acc[3][1] = __builtin_amdgcn_mfma_i32_32x32x32_i8(a[ks], b1[ks], acc[3][1], 0, 0, 0);
    }
    __builtin_amdgcn_s_setprio(0);

    // S2: boundary — counted wait keeps 6 loads in flight
    if (t < NTI - 2)       asm volatile("s_waitcnt vmcnt(6)\n\ts_barrier" ::: "memory");
    else if (t == NTI - 2) asm volatile("s_waitcnt vmcnt(0)\n\ts_barrier" ::: "memory");
    else                   asm volatile("s_barrier" ::: "memory");
  }

  // epilogue: y = acc * xs[row] * scale[col] + bias[col]
  // C/D 32x32: col = lane&31, row = (reg&3) + 8*(reg>>2) + 4*half
  const int colb = (int)n0 + wn * 64 + r5;
#pragma unroll
  for (int mf = 0; mf < 4; ++mf) {
    const size_t rbase = m0 + wm * 128 + mf * 32 + 4 * half;
#pragma unroll
    for (int reg = 0; reg < 16; ++reg) {
      const size_t row = rbase + (reg & 3) + 8 * (reg >> 2);
      const float xsr = xs[row];
      float* cp = C + row * NN + colb;
#pragma unroll
      for (int nf = 0; nf < 2; ++nf) {
        const int col = colb + nf * 32;
        cp[nf * 32] = (float)acc[mf][nf][reg] * xsr * scale[col] + bias[col];
      }
    }
  }
#undef LDFI
}
#endif  // HAVE_I8_MFMA

// ---------------- GEMM, inline-conversion bf16 fallback (no workspace needed) ----------------

__global__ __launch_bounds__(256) void int4lin_gemm_inline(
    const float* __restrict__ X,
    const int* __restrict__ P,
    const float* __restrict__ scale,
    const float* __restrict__ bias,
    float* __restrict__ C)
{
  __shared__ unsigned short As[128 * 64];
  __shared__ unsigned short Bs[128 * 64];

  const int tid  = threadIdx.x;
  const int lane = tid & 63;
  const int wave = tid >> 6;
  const int m0 = blockIdx.y * 128;
  const int n0 = blockIdx.x * 128;
  const int wr = (wave >> 1) * 64;
  const int wc = (wave & 1) * 64;

  f32x4 acc[4][4] = {};

  for (int kt = 0; kt < KK; kt += 64) {
#pragma unroll
    for (int i = 0; i < 8; ++i) {
      const int idx = i * 256 + tid;
      const int row = idx >> 4;
      const int c   = (idx & 15) << 2;
      f32x4 v = *(const f32x4*)(X + (size_t)(m0 + row) * KK + kt + c);
      s16x4 o;
      o[0] = (short)f2bf(v[0]); o[1] = (short)f2bf(v[1]);
      o[2] = (short)f2bf(v[2]); o[3] = (short)f2bf(v[3]);
      *(s16x4*)(As + row * 64 + (c ^ ((row & 7) << 3))) = o;
    }
#pragma unroll
    for (int i = 0; i < 4; ++i) {
      const int idx = i * 256 + tid;
      const int row = idx >> 3;
      const int c   = (idx & 7) << 3;
      i32x4 v = *(const i32x4*)(P + (size_t)(n0 + row) * PKW + ((kt + c) >> 1));
      s16x8 o;
#pragma unroll
      for (int j = 0; j < 4; ++j) {
        const int b = v[j];
        o[2 * j]     = (short)f2bf((float)((b & 15) - 7));
        o[2 * j + 1] = (short)f2bf((float)(((b >> 4) & 15) - 7));
      }
      *(s16x8*)(Bs + row * 64 + (c ^ ((row & 7) << 3))) = o;
    }
    __syncthreads();
#pragma unroll
    for (int kk = 0; kk < 2; ++kk) {
      const int rsel = lane & 15;
      const int ksel = ((((lane >> 4) << 3) + kk * 32)) ^ ((lane & 7) << 3);
      s16x8 af[4], bfr[4];
#pragma unroll
      for (int m = 0; m < 4; ++m)
        af[m] = *(const s16x8*)(As + (wr + m * 16 + rsel) * 64 + ksel);
#pragma unroll
      for (int n = 0; n < 4; ++n)
        bfr[n] = *(const s16x8*)(Bs + (wc + n * 16 + rsel) * 64 + ksel);
#pragma unroll
      for (int m = 0; m < 4; ++m)
#pragma unroll
        for (int n = 0; n < 4; ++n)
          acc[m][n] = __builtin_amdgcn_mfma_f32_16x16x32_bf16(af[m], bfr[n], acc[m][n], 0, 0, 0);
    }
    __syncthreads();
  }

  const int crow = wr + ((lane >> 4) << 2);
  const int ccol = wc + (lane & 15);
#pragma unroll
  for (int n = 0; n < 4; ++n) {
    const int gc = n0 + ccol + n * 16;
    const float sc = scale[gc];
    const float bi = bias[gc];
#pragma unroll
    for (int m = 0; m < 4; ++m) {
      float* cp = C + (size_t)(m0 + crow + m * 16) * NN + gc;
#pragma unroll
      for (int r = 0; r < 4; ++r)
        cp[(size_t)r * NN] = acc[m][n][r] * sc + bi;
    }
  }
}

// ---------------- launch ----------------

extern "C" void kernel_launch(void* const* d_in, const int* in_sizes, int n_in,
                              void* d_out, int out_size, void* d_ws, size_t ws_size,
                              hipStream_t stream) {
  const float* x      = (const float*)d_in[0];
  const int*   packed = (const int*)d_in[1];
  const float* scale  = (const float*)d_in[2];
  const float* bias   = (const float*)d_in[3];
  float* y = (float*)d_out;

#if HAVE_I8_MFMA
  const size_t nXA = (size_t)MM * KK;                  // 32 MiB i8
  const size_t nWB = (size_t)NN * KK;                  // ~43 MiB i8
  const size_t nXS = (size_t)MM * sizeof(float);       // 32 KiB
  if (ws_size >= nXA + nWB + nXS) {
    signed char* xi = (signed char*)d_ws;
    signed char* wi = (signed char*)d_ws + nXA;
    float*       xsv = (float*)((char*)d_ws + nXA + nWB);
    int4lin_quant_x<<<MM, 256, 0, stream>>>(x, xi, xsv);
    int4lin_quant_w<<<2048, 256, 0, stream>>>(packed, wi);
    int4lin_gemm_i8<<<(NN / BN) * (MM / BM), 512, 0, stream>>>(xi, wi, xsv, scale, bias, y);
    return;
  }
#endif
  dim3 grid(NN / 128, MM / 128);
  int4lin_gemm_inline<<<grid, 256, 0, stream>>>(x, packed, scale, bias, y);
}

// Round 9
// 604.063 us; speedup vs baseline: 2.4263x; 2.4263x over previous
//
#include <hip/hip_runtime.h>
#include <hip/hip_bf16.h>

#define MM 8192
#define NN 11008
#define KK 4096
#define PKW 2048    // packed int32 words per output row (each word = ONE byte-pair value)

#define BM 256
#define BN 256
#define BKI 128                 // K per tile (i8)
#define NTI (KK / BKI)          // 32 K-tiles

typedef __attribute__((ext_vector_type(4)))  float f32x4;
typedef __attribute__((ext_vector_type(4)))  int   i32x4;
typedef __attribute__((ext_vector_type(16))) int   i32x16;
typedef __attribute__((ext_vector_type(8)))  short s16x8;
typedef __attribute__((ext_vector_type(4)))  short s16x4;

typedef __attribute__((address_space(3))) unsigned char        lds_u8;
typedef const __attribute__((address_space(1))) unsigned char  glb_u8;

static __device__ __forceinline__ unsigned short f2bf(float f) {
  union { float f; unsigned int u; } v; v.f = f;
  unsigned int u = v.u;
  u += 0x7fffu + ((u >> 16) & 1u);   // RNE
  return (unsigned short)(u >> 16);
}

// ---------------- quantize x: per-row absmax -> i8, PRE-SWIZZLED ----------------
// Row layout: 256 groups of 16 B per row; within each 128-B K-block (8 groups),
// group g stored at g ^ (row&7). GEMM stages linearly, reads with same XOR.

__global__ __launch_bounds__(256) void int4lin_quant_x(
    const float* __restrict__ X, signed char* __restrict__ O, float* __restrict__ xs)
{
  const int row  = blockIdx.x;
  const int t    = threadIdx.x;
  const int lane = t & 63;
  const int wave = t >> 6;
  const float* xr = X + (size_t)row * KK;

  f32x4 v[4];
  float mx = 0.0f;
#pragma unroll
  for (int j = 0; j < 4; ++j) {
    v[j] = *(const f32x4*)(xr + t * 16 + j * 4);
#pragma unroll
    for (int e = 0; e < 4; ++e) mx = fmaxf(mx, fabsf(v[j][e]));
  }
#pragma unroll
  for (int off = 32; off; off >>= 1) mx = fmaxf(mx, __shfl_xor(mx, off));
  __shared__ float red[4];
  if (lane == 0) red[wave] = mx;
  __syncthreads();
  mx = fmaxf(fmaxf(red[0], red[1]), fmaxf(red[2], red[3]));
  mx = fmaxf(mx, 1e-30f);
  const float rs = 127.0f / mx;
  if (t == 0) xs[row] = mx / 127.0f;

  i32x4 o;
#pragma unroll
  for (int w = 0; w < 4; ++w) {
    int acc = 0;
#pragma unroll
    for (int e = 0; e < 4; ++e) {
      int q = __float2int_rn(v[w][e] * rs);
      q = max(-127, min(127, q));
      acc |= (q & 0xff) << (8 * e);
    }
    o[w] = acc;
  }
  signed char* dst = O + (size_t)row * KK + ((t >> 3) << 7) + (((t & 7) ^ (row & 7)) << 4);
  *(i32x4*)dst = o;
}

// ---------------- quantize w: nibbles -> i8 q in [-7,8], PRE-SWIZZLED ----------------

__global__ void int4lin_quant_w(const int* __restrict__ P, signed char* __restrict__ O) {
  const int ntot = NN * 256;       // 16-byte groups
  int i = blockIdx.x * blockDim.x + threadIdx.x;
  const int stride = gridDim.x * blockDim.x;
  for (; i < ntot; i += stride) {
    const int row = i >> 8;
    const int gr  = i & 255;
    const int* src = P + (size_t)row * PKW + gr * 8;   // 8 words -> 16 i8
    i32x4 va = *(const i32x4*)src;
    i32x4 vb = *(const i32x4*)(src + 4);
    i32x4 o;
#pragma unroll
    for (int h = 0; h < 2; ++h) {
      i32x4 w = h ? vb : va;
#pragma unroll
      for (int p = 0; p < 2; ++p) {
        const int b0 = w[2 * p], b1 = w[2 * p + 1];
        const int q0 = (b0 & 15) - 7, q1 = ((b0 >> 4) & 15) - 7;
        const int q2 = (b1 & 15) - 7, q3 = ((b1 >> 4) & 15) - 7;
        o[h * 2 + p] = (q0 & 0xff) | ((q1 & 0xff) << 8) | ((q2 & 0xff) << 16) | ((q3 & 0xff) << 24);
      }
    }
    signed char* dst = O + (size_t)row * KK + ((gr >> 3) << 7) + (((gr & 7) ^ (row & 7)) << 4);
    *(i32x4*)dst = o;
  }
}

// ---------------- 256x256x128 i8 GEMM, R6 ring skeleton ----------------
// Per tile per wave: 32x mfma_i32_32x32x32_i8 (mf 0..3, nf 0..1, ks 0..3).
// Frag read: 16 B at row*128 + ((ks*2+half)^(r5&7))*16, half = lane>>5.
// K-permutation from the swizzle cancels (same (lane,byte)->k map on A and B).
// Ring (8 gloads/tile): SP1: A(t+1) q1,q3 | post-S1: B(t+2) q0-3 + A(t+2) q0,q2.
// Boundary vmcnt(6): tile t+1's newest load has exactly 6 issued after it.
// S1 safety: pre-S1 reads cover all B rows + A q0 (wm0 mf01) and q2 (wm1 mf01);
// post-S1 stages touch only q0,q2,B of the live buffer; wm0/wm1 SP3-SP4 read
// only q1/q3, untouched by post-S1 stores.

__global__ __launch_bounds__(512, 2) void int4lin_gemm_i8(
    const signed char* __restrict__ Ai,   // M x K i8, pre-swizzled
    const signed char* __restrict__ Bi,   // N x K i8, pre-swizzled
    const float* __restrict__ xs,
    const float* __restrict__ scale,
    const float* __restrict__ bias,
    float* __restrict__ C)
{
  __shared__ signed char As[2][BM * BKI];   // 2 x 32 KiB
  __shared__ signed char Bs[2][BN * BKI];   // 2 x 32 KiB -> 128 KiB

  const int tid  = threadIdx.x;
  const int lane = tid & 63;
  const int wave = tid >> 6;
  const int wm = wave >> 2;          // 0..1
  const int wn = wave & 3;           // 0..3

  // T1: bijective XCD swizzle (1376 = 8*172)
  const int bid = blockIdx.x;
  const int swz = (bid & 7) * 172 + (bid >> 3);
  const int bm = swz / 43;
  const int bn = swz - bm * 43;
  const size_t m0 = (size_t)bm * BM;
  const size_t n0 = (size_t)bn * BN;

  const int r5   = lane & 31;        // frag row/col
  const int half = lane >> 5;        // k-half within instruction
  const int rx7  = r5 & 7;           // T2 read-swizzle key

  i32x16 acc[4][2] = {};             // [mf][nf]

  const int arow = wm * 128;         // + mf*32 + r5
  const int brow = wn * 64;          // + nf*32 + r5

#define LDFI(base, row, ks) \
  (*(const i32x4*)((const signed char*)(base) + (size_t)(row) * BKI + ((((ks) * 2 + half) ^ rx7) << 4)))

  const int srow   = tid >> 3;         // 0..63
  const int scolb  = (tid & 7) << 4;   // byte offset within 128-B row

  auto stage_a_q = [&](int buf, int kt, int q) {
    __builtin_amdgcn_global_load_lds(
        (glb_u8*)(Ai + (m0 + q * 64 + srow) * KK + kt + scolb),
        (lds_u8*)((char*)&As[buf][0] + q * 8192 + tid * 16), 16, 0, 0);
  };
  auto stage_b_q = [&](int buf, int kt, int q) {
    __builtin_amdgcn_global_load_lds(
        (glb_u8*)(Bi + (n0 + q * 64 + srow) * KK + kt + scolb),
        (lds_u8*)((char*)&Bs[buf][0] + q * 8192 + tid * 16), 16, 0, 0);
  };

  // -------- prologue: tile0 fully (8), tile1 partially (6); vmcnt(6) --------
#pragma unroll
  for (int q = 0; q < 4; ++q) stage_b_q(0, 0, q);
  stage_a_q(0, 0, 0); stage_a_q(0, 0, 2);
  stage_a_q(0, 0, 1); stage_a_q(0, 0, 3);
#pragma unroll
  for (int q = 0; q < 4; ++q) stage_b_q(1, BKI, q);
  stage_a_q(1, BKI, 0); stage_a_q(1, BKI, 2);
  asm volatile("s_waitcnt vmcnt(6)\n\ts_barrier" ::: "memory");

#pragma unroll 1
  for (int t = 0; t < NTI; ++t) {
    const int rbuf = t & 1;
    const signed char* Ab = &As[rbuf][0];
    const signed char* Bb = &Bs[rbuf][0];
    i32x4 a[4], b0[4], b1[4];

    // SP1: stage A(t+1) late quarters; read B + A mf0; MFMA mf0
    if (t + 1 < NTI) {
      stage_a_q(rbuf ^ 1, (t + 1) * BKI, 1);
      stage_a_q(rbuf ^ 1, (t + 1) * BKI, 3);
    }
#pragma unroll
    for (int ks = 0; ks < 4; ++ks) b0[ks] = LDFI(Bb, brow + r5, ks);
#pragma unroll
    for (int ks = 0; ks < 4; ++ks) b1[ks] = LDFI(Bb, brow + 32 + r5, ks);
#pragma unroll
    for (int ks = 0; ks < 4; ++ks) a[ks] = LDFI(Ab, arow + r5, ks);
    __builtin_amdgcn_s_setprio(1);
#pragma unroll
    for (int ks = 0; ks < 4; ++ks) {
      acc[0][0] = __builtin_amdgcn_mfma_i32_32x32x32_i8(a[ks], b0[ks], acc[0][0], 0, 0, 0);
      acc[0][1] = __builtin_amdgcn_mfma_i32_32x32x32_i8(a[ks], b1[ks], acc[0][1], 0, 0, 0);
    }
    __builtin_amdgcn_s_setprio(0);

    // SP2: read A mf1; MFMA mf1
#pragma unroll
    for (int ks = 0; ks < 4; ++ks) a[ks] = LDFI(Ab, arow + 32 + r5, ks);
    __builtin_amdgcn_s_setprio(1);
#pragma unroll
    for (int ks = 0; ks < 4; ++ks) {
      acc[1][0] = __builtin_amdgcn_mfma_i32_32x32x32_i8(a[ks], b0[ks], acc[1][0], 0, 0, 0);
      acc[1][1] = __builtin_amdgcn_mfma_i32_32x32x32_i8(a[ks], b1[ks], acc[1][1], 0, 0, 0);
    }
    __builtin_amdgcn_s_setprio(0);

    // S1: all waves' B reads + A q0/q2 reads complete
    asm volatile("s_barrier" ::: "memory");

    // post-S1: stage B(t+2) + A(t+2) early into live buffer
    if (t + 2 < NTI) {
#pragma unroll
      for (int q = 0; q < 4; ++q) stage_b_q(rbuf, (t + 2) * BKI, q);
      stage_a_q(rbuf, (t + 2) * BKI, 0);
      stage_a_q(rbuf, (t + 2) * BKI, 2);
    }

    // SP3: read A mf2; MFMA mf2
#pragma unroll
    for (int ks = 0; ks < 4; ++ks) a[ks] = LDFI(Ab, arow + 64 + r5, ks);
    __builtin_amdgcn_s_setprio(1);
#pragma unroll
    for (int ks = 0; ks < 4; ++ks) {
      acc[2][0] = __builtin_amdgcn_mfma_i32_32x32x32_i8(a[ks], b0[ks], acc[2][0], 0, 0, 0);
      acc[2][1] = __builtin_amdgcn_mfma_i32_32x32x32_i8(a[ks], b1[ks], acc[2][1], 0, 0, 0);
    }
    __builtin_amdgcn_s_setprio(0);

    // SP4: read A mf3; MFMA mf3
#pragma unroll
    for (int ks = 0; ks < 4; ++ks) a[ks] = LDFI(Ab, arow + 96 + r5, ks);
    __builtin_amdgcn_s_setprio(1);
#pragma unroll
    for (int ks = 0; ks < 4; ++ks) {
      acc[3][0] = __builtin_amdgcn_mfma_i32_32x32x32_i8(a[ks], b0[ks], acc[3][0], 0, 0, 0);
      acc[3][1] = __builtin_amdgcn_mfma_i32_32x32x32_i8(a[ks], b1[ks], acc[3][1], 0, 0, 0);
    }
    __builtin_amdgcn_s_setprio(0);

    // S2: boundary — counted wait keeps 6 loads in flight
    if (t < NTI - 2)       asm volatile("s_waitcnt vmcnt(6)\n\ts_barrier" ::: "memory");
    else if (t == NTI - 2) asm volatile("s_waitcnt vmcnt(0)\n\ts_barrier" ::: "memory");
    else                   asm volatile("s_barrier" ::: "memory");
  }

  // epilogue: y = acc * xs[row] * scale[col] + bias[col]
  // C/D 32x32: col = lane&31, row = (reg&3) + 8*(reg>>2) + 4*half
  const int colb = (int)n0 + wn * 64 + r5;
#pragma unroll
  for (int mf = 0; mf < 4; ++mf) {
    const size_t rbase = m0 + wm * 128 + mf * 32 + 4 * half;
#pragma unroll
    for (int reg = 0; reg < 16; ++reg) {
      const size_t row = rbase + (reg & 3) + 8 * (reg >> 2);
      const float xsr = xs[row];
      float* cp = C + row * NN + colb;
#pragma unroll
      for (int nf = 0; nf < 2; ++nf) {
        const int col = colb + nf * 32;
        cp[nf * 32] = (float)acc[mf][nf][reg] * xsr * scale[col] + bias[col];
      }
    }
  }
#undef LDFI
}

// ---------------- GEMM, inline-conversion bf16 fallback (no workspace needed) ----------------

__global__ __launch_bounds__(256) void int4lin_gemm_inline(
    const float* __restrict__ X,
    const int* __restrict__ P,
    const float* __restrict__ scale,
    const float* __restrict__ bias,
    float* __restrict__ C)
{
  __shared__ unsigned short As[128 * 64];
  __shared__ unsigned short Bs[128 * 64];

  const int tid  = threadIdx.x;
  const int lane = tid & 63;
  const int wave = tid >> 6;
  const int m0 = blockIdx.y * 128;
  const int n0 = blockIdx.x * 128;
  const int wr = (wave >> 1) * 64;
  const int wc = (wave & 1) * 64;

  f32x4 acc[4][4] = {};

  for (int kt = 0; kt < KK; kt += 64) {
#pragma unroll
    for (int i = 0; i < 8; ++i) {
      const int idx = i * 256 + tid;
      const int row = idx >> 4;
      const int c   = (idx & 15) << 2;
      f32x4 v = *(const f32x4*)(X + (size_t)(m0 + row) * KK + kt + c);
      s16x4 o;
      o[0] = (short)f2bf(v[0]); o[1] = (short)f2bf(v[1]);
      o[2] = (short)f2bf(v[2]); o[3] = (short)f2bf(v[3]);
      *(s16x4*)(As + row * 64 + (c ^ ((row & 7) << 3))) = o;
    }
#pragma unroll
    for (int i = 0; i < 4; ++i) {
      const int idx = i * 256 + tid;
      const int row = idx >> 3;
      const int c   = (idx & 7) << 3;
      i32x4 v = *(const i32x4*)(P + (size_t)(n0 + row) * PKW + ((kt + c) >> 1));
      s16x8 o;
#pragma unroll
      for (int j = 0; j < 4; ++j) {
        const int b = v[j];
        o[2 * j]     = (short)f2bf((float)((b & 15) - 7));
        o[2 * j + 1] = (short)f2bf((float)(((b >> 4) & 15) - 7));
      }
      *(s16x8*)(Bs + row * 64 + (c ^ ((row & 7) << 3))) = o;
    }
    __syncthreads();
#pragma unroll
    for (int kk = 0; kk < 2; ++kk) {
      const int rsel = lane & 15;
      const int ksel = ((((lane >> 4) << 3) + kk * 32)) ^ ((lane & 7) << 3);
      s16x8 af[4], bfr[4];
#pragma unroll
      for (int m = 0; m < 4; ++m)
        af[m] = *(const s16x8*)(As + (wr + m * 16 + rsel) * 64 + ksel);
#pragma unroll
      for (int n = 0; n < 4; ++n)
        bfr[n] = *(const s16x8*)(Bs + (wc + n * 16 + rsel) * 64 + ksel);
#pragma unroll
      for (int m = 0; m < 4; ++m)
#pragma unroll
        for (int n = 0; n < 4; ++n)
          acc[m][n] = __builtin_amdgcn_mfma_f32_16x16x32_bf16(af[m], bfr[n], acc[m][n], 0, 0, 0);
    }
    __syncthreads();
  }

  const int crow = wr + ((lane >> 4) << 2);
  const int ccol = wc + (lane & 15);
#pragma unroll
  for (int n = 0; n < 4; ++n) {
    const int gc = n0 + ccol + n * 16;
    const float sc = scale[gc];
    const float bi = bias[gc];
#pragma unroll
    for (int m = 0; m < 4; ++m) {
      float* cp = C + (size_t)(m0 + crow + m * 16) * NN + gc;
#pragma unroll
      for (int r = 0; r < 4; ++r)
        cp[(size_t)r * NN] = acc[m][n][r] * sc + bi;
    }
  }
}

// ---------------- launch ----------------

extern "C" void kernel_launch(void* const* d_in, const int* in_sizes, int n_in,
                              void* d_out, int out_size, void* d_ws, size_t ws_size,
                              hipStream_t stream) {
  const float* x      = (const float*)d_in[0];
  const int*   packed = (const int*)d_in[1];
  const float* scale  = (const float*)d_in[2];
  const float* bias   = (const float*)d_in[3];
  float* y = (float*)d_out;

  const size_t nXA = (size_t)MM * KK;                  // 32 MiB i8
  const size_t nWB = (size_t)NN * KK;                  // ~43 MiB i8
  const size_t nXS = (size_t)MM * sizeof(float);       // 32 KiB
  if (ws_size >= nXA + nWB + nXS) {
    signed char* xi = (signed char*)d_ws;
    signed char* wi = (signed char*)d_ws + nXA;
    float*       xsv = (float*)((char*)d_ws + nXA + nWB);
    int4lin_quant_x<<<MM, 256, 0, stream>>>(x, xi, xsv);
    int4lin_quant_w<<<2048, 256, 0, stream>>>(packed, wi);
    int4lin_gemm_i8<<<(NN / BN) * (MM / BM), 512, 0, stream>>>(xi, wi, xsv, scale, bias, y);
    return;
  }
  dim3 grid(NN / 128, MM / 128);
  int4lin_gemm_inline<<<grid, 256, 0, stream>>>(x, packed, scale, bias, y);
}